// Round 9
// baseline (312.223 us; speedup 1.0000x reference)
//
#include <hip/hip_runtime.h>
#include <hip/hip_bf16.h>

#define IMAGE_SIZE 416
#define DECODED 64
#define NPIX (IMAGE_SIZE * IMAGE_SIZE)   // 173056
#define M_OBJ 128                        // B*N = 4*32
#define D_IN 64
#define H1 512
#define OUT2 12288                       // 3*64*64

// Diagnostic repeat counts (idempotent; lift kernels above the 40us fill
// floor in the rocprof top-5 so we get real per-kernel counters). REMOVE
// once the breakdown is known.
#define REP_MLP2 8
#define REP_COMP 12

__device__ __forceinline__ int safe_count(const int* cnt) {
    int c = *cnt;
    return min(max(c, 1), 128);
}

// ---------------- Kernel 1: front = mlp1 (blocks 0..127) + wts (block 128) --
// pobj layout per (batch, local-slot) (8 floats): tx, ty, inv_sx, inv_sy,
// weight, global_slot, 0, 0. pcnt[b] = #present in batch b.
__global__ __launch_bounds__(512) void front_kernel(const float* __restrict__ z_what,
                                                    const float* __restrict__ w1,
                                                    const float* __restrict__ b1,
                                                    const float* __restrict__ z_where,
                                                    const int* __restrict__ z_present,
                                                    const float* __restrict__ z_depth,
                                                    float* __restrict__ hid,
                                                    float* __restrict__ pobj,
                                                    int* __restrict__ pcnt,
                                                    int* __restrict__ cnt) {
    const int bx = blockIdx.x;
    const int t = threadIdx.x;
    const int lane = t & 63;
    const int wv = t >> 6;

    // ---- ballot-based presence masks (all blocks compute them; cheap) ----
    const int p = (t < 128) ? z_present[t] : 0;
    const unsigned long long bal = __ballot(p != 0);
    __shared__ unsigned long long smask[8];
    __shared__ int sorig;
    if (lane == 0) smask[wv] = bal;
    if (t == 0) sorig = -1;
    __syncthreads();
    const unsigned long long m0 = smask[0];
    const unsigned long long m1 = smask[1];
    const int cnt0 = __popcll(m0);
    const int count = cnt0 + __popcll(m1);
    // global compact slot for thread t (valid when t<128 && p)
    const unsigned long long below = (wv == 0 ? m0 : m1) & ((lane ? ((1ull << lane) - 1) : 0ull));
    const int gslot = (wv == 0 ? 0 : cnt0) + __popcll(below);

    if (bx == 128) {
        // ---- wts path: softmax weights + STN constants + compact lists ----
        __shared__ float sd[128];
        __shared__ float se[128];
        float d = 0.0f;
        if (t < 128) {
            d = p ? z_depth[t] : -1000.0f;
            sd[t] = d;
        }
        __syncthreads();
        float e = 0.0f;
        if (t < 128) {
            const int b = t >> 5;
            float m = -1e30f;
#pragma unroll
            for (int k = 0; k < 32; ++k) m = fmaxf(m, sd[(b << 5) + k]);
            e = expf(d - m);
            se[t] = e;
        }
        __syncthreads();
        if (t < 128) {
            const int b = t >> 5;
            float s = 0.0f;
#pragma unroll
            for (int k = 0; k < 32; ++k) s += se[(b << 5) + k];
            const float wgt = p ? (e / s) : 0.0f;

            // batch-local compact index
            const unsigned bb32 = (unsigned)(((wv == 0 ? m0 : m1) >> (t & 32)) & 0xFFFFFFFFull);
            const int lb = t & 31;
            const int mb = __popc(bb32 & (lb ? ((1u << lb) - 1u) : 0u));
            const int cnt_b = __popc(bb32);
            if (lb == 0) pcnt[b] = cnt_b;

            if (p) {
                const float xc = z_where[t * 4 + 0];
                const float yc = z_where[t * 4 + 1];
                const float ww = z_where[t * 4 + 2];
                const float hh = z_where[t * 4 + 3];
                float* o = pobj + (size_t)(b * 32 + mb) * 8;
                o[0] = 2.0f * xc - 1.0f;
                o[1] = 2.0f * yc - 1.0f;
                o[2] = 1.0f / fmaxf(ww, 0.001f);
                o[3] = 1.0f / fmaxf(hh, 0.001f);
                o[4] = wgt;
                o[5] = (float)gslot;
                o[6] = 0.0f; o[7] = 0.0f;
            }
            if (t == 0) *cnt = count;
        }
        return;
    }

    // ---- mlp1 path: compact slot bx -> orig row via ballot (no serial scan) --
    if (bx >= count) return;
    if (t < 128 && p && gslot == bx) sorig = t;
    __syncthreads();
    const int orig = sorig;
    if (orig < 0) return;

    const int h = t;                    // 0..511
    const float* zr = z_what + orig * D_IN;   // uniform per block -> scalar loads
    float acc = b1[h];
#pragma unroll
    for (int d = 0; d < D_IN; ++d)
        acc = fmaf(zr[d], w1[d * H1 + h], acc);
    hid[bx * H1 + h] = fmaxf(acc, 0.0f);
}

// ---------------- Kernel 2: dec[ci] = sigmoid(hid[ci] @ w2 + b2) -------------
// In-block split-K (8 kg x 64 cols), hid tile in LDS, XCD col-stripe swizzle.
// REP_MLP2 idempotent repeats for profiling visibility.
__global__ __launch_bounds__(512) void mlp2_fused(const float* __restrict__ hid,
                                                  const float* __restrict__ w2,
                                                  const float* __restrict__ b2,
                                                  float* __restrict__ dec,
                                                  const int* __restrict__ cnt) {
    const int count = safe_count(cnt);

    const int lin = blockIdx.x + blockIdx.y * gridDim.x;   // 0..1535
    const int jt  = (lin & 7) * 24 + ((lin >> 3) % 24);    // col-tile 0..191
    const int rt  = lin / 192;                             // row-tile 0..7
    const int ci0 = rt * 16;
    if (ci0 >= count) return;

    const int kg = threadIdx.x >> 6;          // k-group 0..7
    const int c  = threadIdx.x & 63;
    const int j  = jt * 64 + c;
    const int kbase = __builtin_amdgcn_readfirstlane(kg * 64);

    __shared__ float smem[8192];              // 32 KB: hid tile, then sred

    for (int rep = 0; rep < REP_MLP2; ++rep) {
        asm volatile("" ::: "memory");        // force real re-execution per rep

        {
            const float4* g4 = (const float4*)(hid + ci0 * H1);
            float4* s4 = (float4*)smem;
#pragma unroll
            for (int i = 0; i < 4; ++i)
                s4[threadIdx.x + i * 512] = g4[threadIdx.x + i * 512];
        }
        __syncthreads();

        float acc[16];
#pragma unroll
        for (int r = 0; r < 16; ++r) acc[r] = 0.0f;

        const float* wp = w2 + (size_t)kbase * OUT2 + j;
        float wa[8], wb[8];
#pragma unroll
        for (int u = 0; u < 8; ++u) wa[u] = wp[(size_t)u * OUT2];

        for (int k0 = 0; k0 < 64; k0 += 16) {
#pragma unroll
            for (int u = 0; u < 8; ++u) wb[u] = wp[(size_t)(k0 + 8 + u) * OUT2];
#pragma unroll
            for (int r = 0; r < 16; ++r) {
                const float4 h0 = *(const float4*)&smem[r * 512 + kbase + k0];
                const float4 h1 = *(const float4*)&smem[r * 512 + kbase + k0 + 4];
                acc[r] = fmaf(h0.x, wa[0], acc[r]);
                acc[r] = fmaf(h0.y, wa[1], acc[r]);
                acc[r] = fmaf(h0.z, wa[2], acc[r]);
                acc[r] = fmaf(h0.w, wa[3], acc[r]);
                acc[r] = fmaf(h1.x, wa[4], acc[r]);
                acc[r] = fmaf(h1.y, wa[5], acc[r]);
                acc[r] = fmaf(h1.z, wa[6], acc[r]);
                acc[r] = fmaf(h1.w, wa[7], acc[r]);
            }
            if (k0 + 16 < 64) {
#pragma unroll
                for (int u = 0; u < 8; ++u) wa[u] = wp[(size_t)(k0 + 16 + u) * OUT2];
            }
#pragma unroll
            for (int r = 0; r < 16; ++r) {
                const float4 h0 = *(const float4*)&smem[r * 512 + kbase + k0 + 8];
                const float4 h1 = *(const float4*)&smem[r * 512 + kbase + k0 + 12];
                acc[r] = fmaf(h0.x, wb[0], acc[r]);
                acc[r] = fmaf(h0.y, wb[1], acc[r]);
                acc[r] = fmaf(h0.z, wb[2], acc[r]);
                acc[r] = fmaf(h0.w, wb[3], acc[r]);
                acc[r] = fmaf(h1.x, wb[4], acc[r]);
                acc[r] = fmaf(h1.y, wb[5], acc[r]);
                acc[r] = fmaf(h1.z, wb[6], acc[r]);
                acc[r] = fmaf(h1.w, wb[7], acc[r]);
            }
        }

        __syncthreads();                      // done reading hid tile
        float (*sred)[16][64] = (float (*)[16][64])smem;
#pragma unroll
        for (int r = 0; r < 16; ++r) sred[kg][r][c] = acc[r];
        __syncthreads();

        const int r0 = kg;
        float s0 = 0.0f, s1 = 0.0f;
#pragma unroll
        for (int g = 0; g < 8; ++g) {
            s0 += sred[g][r0][c];
            s1 += sred[g][r0 + 8][c];
        }
        const float bb = b2[j];
        const int rmax = min(16, count - ci0);
        if (r0 < rmax)
            dec[(size_t)(ci0 + r0) * OUT2 + j] = 1.0f / (1.0f + __expf(-(s0 + bb)));
        if (r0 + 8 < rmax)
            dec[(size_t)(ci0 + r0 + 8) * OUT2 + j] = 1.0f / (1.0f + __expf(-(s1 + bb)));
        __syncthreads();                      // sred free before next rep stage
    }
}

// ---------------- Kernel 3: composite --------------------------------------
// Per-batch compacted object list read via uniform (scalar-path) loads; no LDS.
__global__ __launch_bounds__(256) void composite_kernel(const float* __restrict__ dec,
                                                        const float* __restrict__ pobj,
                                                        const int* __restrict__ pcnt,
                                                        float* __restrict__ out) {
    const int pix = blockIdx.x * 256 + threadIdx.x;  // 0..173055
    const int b = blockIdx.y;
    const int h = pix / IMAGE_SIZE;
    const int w = pix - h * IMAGE_SIZE;

    const int cb = min(max(pcnt[b], 0), 32);
    const float* po = pobj + (size_t)b * 32 * 8;

    const float u = fmaf((float)w, 2.0f / 415.0f, -1.0f);
    const float v = fmaf((float)h, 2.0f / 415.0f, -1.0f);

    for (int rep = 0; rep < REP_COMP; ++rep) {
        asm volatile("" ::: "memory");        // force real re-execution per rep

        float a0 = 0.0f, a1 = 0.0f, a2 = 0.0f;

        for (int m_ = 0; m_ < cb; ++m_) {
            const float4 A = *(const float4*)(po + m_ * 8);      // uniform -> s_load
            const float4 B = *(const float4*)(po + m_ * 8 + 4);
            const float gx = (u - A.x) * A.z;
            const float gy = (v - A.y) * A.w;
            const float px = (gx + 1.0f) * (0.5f * (DECODED - 1));  // *31.5
            const float py = (gy + 1.0f) * (0.5f * (DECODED - 1));
            if (px <= -1.0f || px >= (float)DECODED || py <= -1.0f || py >= (float)DECODED)
                continue;

            const float x0f = floorf(px), y0f = floorf(py);
            const int x0 = (int)x0f, y0 = (int)y0f;
            const float wx1 = px - x0f, wx0 = 1.0f - wx1;
            const float wy1 = py - y0f, wy0 = 1.0f - wy1;

            const bool vx0 = (x0 >= 0) & (x0 <= DECODED - 1);
            const bool vx1 = (x0 + 1 >= 0) & (x0 + 1 <= DECODED - 1);
            const bool vy0 = (y0 >= 0) & (y0 <= DECODED - 1);
            const bool vy1 = (y0 + 1 >= 0) & (y0 + 1 <= DECODED - 1);

            const int xc0 = min(max(x0, 0), DECODED - 1);
            const int xc1 = min(max(x0 + 1, 0), DECODED - 1);
            const int yc0 = min(max(y0, 0), DECODED - 1);
            const int yc1 = min(max(y0 + 1, 0), DECODED - 1);

            const float w00 = wx0 * wy0 * (float)(vx0 && vy0);
            const float w10 = wx1 * wy0 * (float)(vx1 && vy0);
            const float w01 = wx0 * wy1 * (float)(vx0 && vy1);
            const float w11 = wx1 * wy1 * (float)(vx1 && vy1);

            const int slot = min(max((int)B.y, 0), 127);
            const float wgt = B.x;
            const float* base = dec + (size_t)slot * OUT2;
            const int i00 = yc0 * DECODED + xc0;
            const int i10 = yc0 * DECODED + xc1;
            const int i01 = yc1 * DECODED + xc0;
            const int i11 = yc1 * DECODED + xc1;

            {
                const float* pp = base;
                float g = w00 * pp[i00] + w10 * pp[i10] + w01 * pp[i01] + w11 * pp[i11];
                a0 = fmaf(wgt, g, a0);
            }
            {
                const float* pp = base + 4096;
                float g = w00 * pp[i00] + w10 * pp[i10] + w01 * pp[i01] + w11 * pp[i11];
                a1 = fmaf(wgt, g, a1);
            }
            {
                const float* pp = base + 8192;
                float g = w00 * pp[i00] + w10 * pp[i10] + w01 * pp[i01] + w11 * pp[i11];
                a2 = fmaf(wgt, g, a2);
            }
        }

        out[((size_t)(b * 3 + 0) * IMAGE_SIZE + h) * IMAGE_SIZE + w] = a0;
        out[((size_t)(b * 3 + 1) * IMAGE_SIZE + h) * IMAGE_SIZE + w] = a1;
        out[((size_t)(b * 3 + 2) * IMAGE_SIZE + h) * IMAGE_SIZE + w] = a2;
    }
}

extern "C" void kernel_launch(void* const* d_in, const int* in_sizes, int n_in,
                              void* d_out, int out_size, void* d_ws, size_t ws_size,
                              hipStream_t stream) {
    const float* z_where   = (const float*)d_in[0];   // [4,32,4]
    const int*   z_present = (const int*)d_in[1];     // [4,32,1]
    const float* z_what    = (const float*)d_in[2];   // [4,32,64]
    const float* z_depth   = (const float*)d_in[3];   // [4,32,1]
    const float* w1 = (const float*)d_in[4];          // [64,512]
    const float* b1 = (const float*)d_in[5];          // [512]
    const float* w2 = (const float*)d_in[6];          // [512,12288]
    const float* b2 = (const float*)d_in[7];          // [12288]
    float* out = (float*)d_out;                       // [4,3,416,416] f32

    char* ws = (char*)d_ws;
    float* dec  = (float*)ws;                         // 6,291,456 B (compact slot)
    float* hid  = (float*)(ws + 6291456);             //   262,144 B (compact slot)
    float* pobj = (float*)(ws + 6553600);             //     4,096 B
    int*  pcnt  = (int*)(ws + 6557696);               //       256 B (pad)
    int*  cnt   = (int*)(ws + 6557952);               //       256 B

    front_kernel<<<129, 512, 0, stream>>>(z_what, w1, b1, z_where, z_present,
                                          z_depth, hid, pobj, pcnt, cnt);
    mlp2_fused<<<dim3(192, 8), 512, 0, stream>>>(hid, w2, b2, dec, cnt);
    composite_kernel<<<dim3(NPIX / 256, 4), 256, 0, stream>>>(dec, pobj, pcnt, out);
}

// Round 10
// 41.389 us; speedup vs baseline: 7.5436x; 7.5436x over previous
//
#include <hip/hip_runtime.h>
#include <hip/hip_bf16.h>

#define IMAGE_SIZE 416
#define DECODED 64
#define NPIX (IMAGE_SIZE * IMAGE_SIZE)   // 173056
#define M_OBJ 128                        // B*N = 4*32
#define D_IN 64
#define H1 512
#define OUT2 12288                       // 3*64*64

__device__ __forceinline__ int safe_count(const int* cnt) {
    int c = *cnt;
    return min(max(c, 1), 128);
}

#define FMA4(ACC, S, W)                      \
    ACC.x = fmaf(S, W.x, ACC.x);             \
    ACC.y = fmaf(S, W.y, ACC.y);             \
    ACC.z = fmaf(S, W.z, ACC.z);             \
    ACC.w = fmaf(S, W.w, ACC.w);

#define ADD4(ACC, W)                         \
    ACC.x += W.x; ACC.y += W.y;              \
    ACC.z += W.z; ACC.w += W.w;

// ---------------- Kernel 1: front = mlp1 (blocks 0..127) + wts (block 128) --
// pobj per (batch, local-slot): tx, ty, inv_sx, inv_sy, weight, global_slot,0,0
__global__ __launch_bounds__(512) void front_kernel(const float* __restrict__ z_what,
                                                    const float* __restrict__ w1,
                                                    const float* __restrict__ b1,
                                                    const float* __restrict__ z_where,
                                                    const int* __restrict__ z_present,
                                                    const float* __restrict__ z_depth,
                                                    float* __restrict__ hid,
                                                    float* __restrict__ pobj,
                                                    int* __restrict__ pcnt,
                                                    int* __restrict__ cnt) {
    const int bx = blockIdx.x;
    const int t = threadIdx.x;
    const int lane = t & 63;
    const int wv = t >> 6;

    const int p = (t < 128) ? z_present[t] : 0;
    const unsigned long long bal = __ballot(p != 0);
    __shared__ unsigned long long smask[8];
    __shared__ int sorig;
    if (lane == 0) smask[wv] = bal;
    if (t == 0) sorig = -1;
    __syncthreads();
    const unsigned long long m0 = smask[0];
    const unsigned long long m1 = smask[1];
    const int cnt0 = __popcll(m0);
    const int count = cnt0 + __popcll(m1);
    const unsigned long long below = (wv == 0 ? m0 : m1) & ((lane ? ((1ull << lane) - 1) : 0ull));
    const int gslot = (wv == 0 ? 0 : cnt0) + __popcll(below);

    if (bx == 128) {
        __shared__ float sd[128];
        __shared__ float se[128];
        float d = 0.0f;
        if (t < 128) {
            d = p ? z_depth[t] : -1000.0f;
            sd[t] = d;
        }
        __syncthreads();
        float e = 0.0f;
        if (t < 128) {
            const int b = t >> 5;
            float m = -1e30f;
#pragma unroll
            for (int k = 0; k < 32; ++k) m = fmaxf(m, sd[(b << 5) + k]);
            e = expf(d - m);
            se[t] = e;
        }
        __syncthreads();
        if (t < 128) {
            const int b = t >> 5;
            float s = 0.0f;
#pragma unroll
            for (int k = 0; k < 32; ++k) s += se[(b << 5) + k];
            const float wgt = p ? (e / s) : 0.0f;

            const unsigned bb32 = (unsigned)(((wv == 0 ? m0 : m1) >> (t & 32)) & 0xFFFFFFFFull);
            const int lb = t & 31;
            const int mb = __popc(bb32 & (lb ? ((1u << lb) - 1u) : 0u));
            const int cnt_b = __popc(bb32);
            if (lb == 0) pcnt[b] = cnt_b;

            if (p) {
                const float xc = z_where[t * 4 + 0];
                const float yc = z_where[t * 4 + 1];
                const float ww = z_where[t * 4 + 2];
                const float hh = z_where[t * 4 + 3];
                float* o = pobj + (size_t)(b * 32 + mb) * 8;
                o[0] = 2.0f * xc - 1.0f;
                o[1] = 2.0f * yc - 1.0f;
                o[2] = 1.0f / fmaxf(ww, 0.001f);
                o[3] = 1.0f / fmaxf(hh, 0.001f);
                o[4] = wgt;
                o[5] = (float)gslot;
                o[6] = 0.0f; o[7] = 0.0f;
            }
            if (t == 0) *cnt = count;
        }
        return;
    }

    if (bx >= count) return;
    if (t < 128 && p && gslot == bx) sorig = t;
    __syncthreads();
    const int orig = sorig;
    if (orig < 0) return;

    const int h = t;                    // 0..511
    const float* zr = z_what + orig * D_IN;   // uniform -> scalar loads
    float acc = b1[h];
#pragma unroll
    for (int d = 0; d < D_IN; ++d)
        acc = fmaf(zr[d], w1[d * H1 + h], acc);
    hid[bx * H1 + h] = fmaxf(acc, 0.0f);
}

// ---------------- Kernel 2: dec[ci] = sigmoid(hid[ci] @ w2 + b2) -------------
// 512 thr = 8 k-groups(waves) x 64 lanes. Per thread: 8 rows x 8 cols
// (two float4 banks), K'=64. Per 4k window: 8 uniform ds_read_b128 vs 256 FMA
// -> VALU-dominant (R8 profile showed the old 1:4 mix was LDS-pipe-bound).
// Block covers 512 cols; grid (24 col-tiles, 16 row-tiles of 8 rows).
// XCD swizzle: each XCD owns a 3-col-tile stripe (3 MB of w2, L2-resident).
// Split-8 partials reduced via 3-round LDS tree in 64 KB (aliased over hid).
__global__ __launch_bounds__(512, 2) void mlp2_fused(const float* __restrict__ hid,
                                                     const float* __restrict__ w2,
                                                     const float* __restrict__ b2,
                                                     float* __restrict__ dec,
                                                     const int* __restrict__ cnt) {
    const int count = safe_count(cnt);

    const int lin = blockIdx.x + blockIdx.y * gridDim.x;   // 0..383
    const int jt  = (lin & 7) * 3 + ((lin >> 3) % 3);      // col-tile 0..23
    const int rt  = lin / 24;                              // row-tile 0..15
    const int ci0 = rt * 8;
    if (ci0 >= count) return;

    const int tid  = threadIdx.x;
    const int kg   = tid >> 6;            // 0..7 (one wave per k-group)
    const int lane = tid & 63;
    const int kbase = kg * 64;
    const int j0 = jt * 512 + lane * 4;   // cols j0..j0+3 and j0+256..j0+259

    __shared__ float smem[16384];         // 64 KB; [0,4096) = hid tile in main loop

    // ---- stage hid[ci0..ci0+8)[0..512) (16 KB), coalesced float4 ----
    {
        const float4* g4 = (const float4*)(hid + (size_t)ci0 * H1);
        float4* s4 = (float4*)smem;
        s4[tid] = g4[tid];
        s4[tid + 512] = g4[tid + 512];
    }
    __syncthreads();

    float4 accA[8], accB[8];
#pragma unroll
    for (int r = 0; r < 8; ++r) {
        accA[r] = make_float4(0.f, 0.f, 0.f, 0.f);
        accB[r] = make_float4(0.f, 0.f, 0.f, 0.f);
    }

    const float4* wp4 = (const float4*)w2;
    const unsigned baseA = (unsigned)kbase * 3072u + (unsigned)(jt * 128 + lane);

    float4 wa0[4], wa1[4], wb0[4], wb1[4];
#pragma unroll
    for (int u = 0; u < 4; ++u) {
        wa0[u] = wp4[baseA + (unsigned)u * 3072u];
        wa1[u] = wp4[baseA + (unsigned)u * 3072u + 64u];
    }

    for (int k0 = 0; k0 < 64; k0 += 8) {
        // prefetch k0+4..k0+7
#pragma unroll
        for (int u = 0; u < 4; ++u) {
            wb0[u] = wp4[baseA + (unsigned)(k0 + 4 + u) * 3072u];
            wb1[u] = wp4[baseA + (unsigned)(k0 + 4 + u) * 3072u + 64u];
        }
#pragma unroll
        for (int r = 0; r < 8; ++r) {
            const float4 h = *(const float4*)&smem[r * 512 + kbase + k0];
            FMA4(accA[r], h.x, wa0[0]); FMA4(accB[r], h.x, wa1[0]);
            FMA4(accA[r], h.y, wa0[1]); FMA4(accB[r], h.y, wa1[1]);
            FMA4(accA[r], h.z, wa0[2]); FMA4(accB[r], h.z, wa1[2]);
            FMA4(accA[r], h.w, wa0[3]); FMA4(accB[r], h.w, wa1[3]);
        }
        if (k0 + 8 < 64) {
#pragma unroll
            for (int u = 0; u < 4; ++u) {
                wa0[u] = wp4[baseA + (unsigned)(k0 + 8 + u) * 3072u];
                wa1[u] = wp4[baseA + (unsigned)(k0 + 8 + u) * 3072u + 64u];
            }
        }
#pragma unroll
        for (int r = 0; r < 8; ++r) {
            const float4 h = *(const float4*)&smem[r * 512 + kbase + k0 + 4];
            FMA4(accA[r], h.x, wb0[0]); FMA4(accB[r], h.x, wb1[0]);
            FMA4(accA[r], h.y, wb0[1]); FMA4(accB[r], h.y, wb1[1]);
            FMA4(accA[r], h.z, wb0[2]); FMA4(accB[r], h.z, wb1[2]);
            FMA4(accA[r], h.w, wb0[3]); FMA4(accB[r], h.w, wb1[3]);
        }
    }

    // ---- split-8 reduction: 3-round LDS tree (bufs alias the hid tile) ----
    __syncthreads();                      // hid tile dead
    // buf g at smem + g*4096, layout [r][512] floats
    if (kg >= 4) {
        float* b = smem + (kg - 4) * 4096;
#pragma unroll
        for (int r = 0; r < 8; ++r) {
            *(float4*)&b[r * 512 + lane * 4] = accA[r];
            *(float4*)&b[r * 512 + 256 + lane * 4] = accB[r];
        }
    }
    __syncthreads();
    if (kg < 4) {
        const float* b = smem + kg * 4096;
#pragma unroll
        for (int r = 0; r < 8; ++r) {
            const float4 pA = *(const float4*)&b[r * 512 + lane * 4];
            const float4 pB = *(const float4*)&b[r * 512 + 256 + lane * 4];
            ADD4(accA[r], pA); ADD4(accB[r], pB);
        }
    }
    __syncthreads();
    if (kg == 2 || kg == 3) {
        float* b = smem + (kg - 2) * 4096;
#pragma unroll
        for (int r = 0; r < 8; ++r) {
            *(float4*)&b[r * 512 + lane * 4] = accA[r];
            *(float4*)&b[r * 512 + 256 + lane * 4] = accB[r];
        }
    }
    __syncthreads();
    if (kg < 2) {
        const float* b = smem + kg * 4096;
#pragma unroll
        for (int r = 0; r < 8; ++r) {
            const float4 pA = *(const float4*)&b[r * 512 + lane * 4];
            const float4 pB = *(const float4*)&b[r * 512 + 256 + lane * 4];
            ADD4(accA[r], pA); ADD4(accB[r], pB);
        }
    }
    __syncthreads();
    if (kg == 1) {
        float* b = smem;
#pragma unroll
        for (int r = 0; r < 8; ++r) {
            *(float4*)&b[r * 512 + lane * 4] = accA[r];
            *(float4*)&b[r * 512 + 256 + lane * 4] = accB[r];
        }
    }
    __syncthreads();
    if (kg == 0) {
        const float* b = smem;
        const float4 bbA = *(const float4*)&b2[j0];
        const float4 bbB = *(const float4*)&b2[j0 + 256];
        const int rmax = count - ci0;
#pragma unroll
        for (int r = 0; r < 8; ++r) {
            if (r < rmax) {
                const float4 pA = *(const float4*)&b[r * 512 + lane * 4];
                const float4 pB = *(const float4*)&b[r * 512 + 256 + lane * 4];
                float4 xA, xB;
                xA.x = accA[r].x + pA.x + bbA.x;
                xA.y = accA[r].y + pA.y + bbA.y;
                xA.z = accA[r].z + pA.z + bbA.z;
                xA.w = accA[r].w + pA.w + bbA.w;
                xB.x = accB[r].x + pB.x + bbB.x;
                xB.y = accB[r].y + pB.y + bbB.y;
                xB.z = accB[r].z + pB.z + bbB.z;
                xB.w = accB[r].w + pB.w + bbB.w;
                float4 oA, oB;
                oA.x = 1.0f / (1.0f + __expf(-xA.x));
                oA.y = 1.0f / (1.0f + __expf(-xA.y));
                oA.z = 1.0f / (1.0f + __expf(-xA.z));
                oA.w = 1.0f / (1.0f + __expf(-xA.w));
                oB.x = 1.0f / (1.0f + __expf(-xB.x));
                oB.y = 1.0f / (1.0f + __expf(-xB.y));
                oB.z = 1.0f / (1.0f + __expf(-xB.z));
                oB.w = 1.0f / (1.0f + __expf(-xB.w));
                *(float4*)&dec[(size_t)(ci0 + r) * OUT2 + j0] = oA;
                *(float4*)&dec[(size_t)(ci0 + r) * OUT2 + j0 + 256] = oB;
            }
        }
    }
}

// ---------------- Kernel 3: composite --------------------------------------
__global__ __launch_bounds__(256) void composite_kernel(const float* __restrict__ dec,
                                                        const float* __restrict__ pobj,
                                                        const int* __restrict__ pcnt,
                                                        float* __restrict__ out) {
    const int pix = blockIdx.x * 256 + threadIdx.x;  // 0..173055
    const int b = blockIdx.y;
    const int h = pix / IMAGE_SIZE;
    const int w = pix - h * IMAGE_SIZE;

    const int cb = min(max(pcnt[b], 0), 32);
    const float* po = pobj + (size_t)b * 32 * 8;

    const float u = fmaf((float)w, 2.0f / 415.0f, -1.0f);
    const float v = fmaf((float)h, 2.0f / 415.0f, -1.0f);

    float a0 = 0.0f, a1 = 0.0f, a2 = 0.0f;

    for (int m_ = 0; m_ < cb; ++m_) {
        const float4 A = *(const float4*)(po + m_ * 8);      // uniform -> s_load
        const float4 B = *(const float4*)(po + m_ * 8 + 4);
        const float gx = (u - A.x) * A.z;
        const float gy = (v - A.y) * A.w;
        const float px = (gx + 1.0f) * (0.5f * (DECODED - 1));  // *31.5
        const float py = (gy + 1.0f) * (0.5f * (DECODED - 1));
        if (px <= -1.0f || px >= (float)DECODED || py <= -1.0f || py >= (float)DECODED)
            continue;

        const float x0f = floorf(px), y0f = floorf(py);
        const int x0 = (int)x0f, y0 = (int)y0f;
        const float wx1 = px - x0f, wx0 = 1.0f - wx1;
        const float wy1 = py - y0f, wy0 = 1.0f - wy1;

        const bool vx0 = (x0 >= 0) & (x0 <= DECODED - 1);
        const bool vx1 = (x0 + 1 >= 0) & (x0 + 1 <= DECODED - 1);
        const bool vy0 = (y0 >= 0) & (y0 <= DECODED - 1);
        const bool vy1 = (y0 + 1 >= 0) & (y0 + 1 <= DECODED - 1);

        const int xc0 = min(max(x0, 0), DECODED - 1);
        const int xc1 = min(max(x0 + 1, 0), DECODED - 1);
        const int yc0 = min(max(y0, 0), DECODED - 1);
        const int yc1 = min(max(y0 + 1, 0), DECODED - 1);

        const float w00 = wx0 * wy0 * (float)(vx0 && vy0);
        const float w10 = wx1 * wy0 * (float)(vx1 && vy0);
        const float w01 = wx0 * wy1 * (float)(vx0 && vy1);
        const float w11 = wx1 * wy1 * (float)(vx1 && vy1);

        const int slot = min(max((int)B.y, 0), 127);
        const float wgt = B.x;
        const float* base = dec + (size_t)slot * OUT2;
        const int i00 = yc0 * DECODED + xc0;
        const int i10 = yc0 * DECODED + xc1;
        const int i01 = yc1 * DECODED + xc0;
        const int i11 = yc1 * DECODED + xc1;

        {
            const float* pp = base;
            float g = w00 * pp[i00] + w10 * pp[i10] + w01 * pp[i01] + w11 * pp[i11];
            a0 = fmaf(wgt, g, a0);
        }
        {
            const float* pp = base + 4096;
            float g = w00 * pp[i00] + w10 * pp[i10] + w01 * pp[i01] + w11 * pp[i11];
            a1 = fmaf(wgt, g, a1);
        }
        {
            const float* pp = base + 8192;
            float g = w00 * pp[i00] + w10 * pp[i10] + w01 * pp[i01] + w11 * pp[i11];
            a2 = fmaf(wgt, g, a2);
        }
    }

    out[((size_t)(b * 3 + 0) * IMAGE_SIZE + h) * IMAGE_SIZE + w] = a0;
    out[((size_t)(b * 3 + 1) * IMAGE_SIZE + h) * IMAGE_SIZE + w] = a1;
    out[((size_t)(b * 3 + 2) * IMAGE_SIZE + h) * IMAGE_SIZE + w] = a2;
}

extern "C" void kernel_launch(void* const* d_in, const int* in_sizes, int n_in,
                              void* d_out, int out_size, void* d_ws, size_t ws_size,
                              hipStream_t stream) {
    const float* z_where   = (const float*)d_in[0];   // [4,32,4]
    const int*   z_present = (const int*)d_in[1];     // [4,32,1]
    const float* z_what    = (const float*)d_in[2];   // [4,32,64]
    const float* z_depth   = (const float*)d_in[3];   // [4,32,1]
    const float* w1 = (const float*)d_in[4];          // [64,512]
    const float* b1 = (const float*)d_in[5];          // [512]
    const float* w2 = (const float*)d_in[6];          // [512,12288]
    const float* b2 = (const float*)d_in[7];          // [12288]
    float* out = (float*)d_out;                       // [4,3,416,416] f32

    char* ws = (char*)d_ws;
    float* dec  = (float*)ws;                         // 6,291,456 B (compact slot)
    float* hid  = (float*)(ws + 6291456);             //   262,144 B (compact slot)
    float* pobj = (float*)(ws + 6553600);             //     4,096 B
    int*  pcnt  = (int*)(ws + 6557696);               //       256 B (pad)
    int*  cnt   = (int*)(ws + 6557952);               //       256 B

    front_kernel<<<129, 512, 0, stream>>>(z_what, w1, b1, z_where, z_present,
                                          z_depth, hid, pobj, pcnt, cnt);
    mlp2_fused<<<dim3(24, 16), 512, 0, stream>>>(hid, w2, b2, dec, cnt);
    composite_kernel<<<dim3(NPIX / 256, 4), 256, 0, stream>>>(dec, pobj, pcnt, out);
}